// Round 1
// baseline (16997.693 us; speedup 1.0000x reference)
//
#include <hip/hip_runtime.h>
#include <math.h>

// GPT-2 small forward, fp32 correctness-first baseline.
// V=50257 C=768 L=12 H=12 B=2 T=1024 HD=64
#define VV 50257
#define CC 768
#define LL 12
#define HH 12
#define TT 1024
#define BB 2
#define BT 2048          // B*T
#define HD 64

__device__ __forceinline__ float wave_sum(float v) {
#pragma unroll
    for (int off = 1; off < 64; off <<= 1) v += __shfl_xor(v, off, 64);
    return v;
}
__device__ __forceinline__ float wave_max(float v) {
#pragma unroll
    for (int off = 1; off < 64; off <<= 1) v = fmaxf(v, __shfl_xor(v, off, 64));
    return v;
}

// ---------------- embedding: x = wte[idx] + wpe[t] ----------------
__global__ __launch_bounds__(256) void embed_k(const int* __restrict__ idx,
                                               const float* __restrict__ wte,
                                               const float* __restrict__ wpe,
                                               float* __restrict__ x) {
    int row = blockIdx.x;                 // 0..BT-1
    int t = row & (TT - 1);
    long tok = idx[row];
    const float* a = wte + tok * (long)CC;
    const float* p = wpe + (long)t * CC;
    float* d = x + (long)row * CC;
    for (int c = threadIdx.x; c < CC; c += 256) d[c] = a[c] + p[c];
}

// ---------------- layernorm (row per block, C=768, block=256) ----------------
__global__ __launch_bounds__(256) void ln_k(const float* __restrict__ in,
                                            const float* __restrict__ w,
                                            const float* __restrict__ b,
                                            float* __restrict__ out) {
    int row = blockIdx.x;
    const float* src = in + (long)row * CC;
    float* dst = out + (long)row * CC;
    float v[3];
    float s = 0.f, sq = 0.f;
#pragma unroll
    for (int i = 0; i < 3; i++) {
        v[i] = src[threadIdx.x + 256 * i];
        s += v[i];
        sq += v[i] * v[i];
    }
    s = wave_sum(s);
    sq = wave_sum(sq);
    __shared__ float ls[4], lq[4];
    int wid = threadIdx.x >> 6, lane = threadIdx.x & 63;
    if (lane == 0) { ls[wid] = s; lq[wid] = sq; }
    __syncthreads();
    s = ls[0] + ls[1] + ls[2] + ls[3];
    sq = lq[0] + lq[1] + lq[2] + lq[3];
    float mean = s * (1.f / CC);
    float var = sq * (1.f / CC) - mean * mean;
    float rstd = rsqrtf(var + 1e-5f);
#pragma unroll
    for (int i = 0; i < 3; i++) {
        int c = threadIdx.x + 256 * i;
        dst[c] = (v[i] - mean) * rstd * w[c] + b[c];
    }
}

// ---------------- GEMM NN: out[M,N] = A[M,K] @ W[K,N] + bias (opt gelu / +res) ----
// BM=BN=64, BK=16, 256 threads, 4x4 per thread. M = gridDim.y*64 (always 2048).
template <bool GELU, bool RES>
__global__ __launch_bounds__(256) void gemm_nn(const float* __restrict__ A,
                                               const float* __restrict__ W,
                                               const float* __restrict__ bias,
                                               const float* __restrict__ res,
                                               float* __restrict__ out,
                                               int N, int K) {
    __shared__ float As[16][64];
    __shared__ float Bs[16][64];
    int tid = threadIdx.x;
    int tx = tid & 15, ty = tid >> 4;
    int bm = blockIdx.y * 64, bn = blockIdx.x * 64;
    float acc[4][4] = {};
    int arow = tid >> 2, acol = (tid & 3) * 4;   // A tile 64x16
    int brow = tid >> 4, bcol = (tid & 15) * 4;  // W tile 16x64

    for (int k0 = 0; k0 < K; k0 += 16) {
        float4 av = *(const float4*)&A[(long)(bm + arow) * K + k0 + acol];
        float4 wv = *(const float4*)&W[(long)(k0 + brow) * N + bn + bcol];
        As[acol + 0][arow] = av.x;
        As[acol + 1][arow] = av.y;
        As[acol + 2][arow] = av.z;
        As[acol + 3][arow] = av.w;
        *(float4*)&Bs[brow][bcol] = wv;
        __syncthreads();
#pragma unroll
        for (int kk = 0; kk < 16; kk++) {
            float4 a4 = *(const float4*)&As[kk][ty * 4];
            float4 w4 = *(const float4*)&Bs[kk][tx * 4];
            float am[4] = {a4.x, a4.y, a4.z, a4.w};
            float wn[4] = {w4.x, w4.y, w4.z, w4.w};
#pragma unroll
            for (int i = 0; i < 4; i++)
#pragma unroll
                for (int j = 0; j < 4; j++) acc[i][j] = fmaf(am[i], wn[j], acc[i][j]);
        }
        __syncthreads();
    }
#pragma unroll
    for (int i = 0; i < 4; i++) {
        int m = bm + ty * 4 + i;
#pragma unroll
        for (int j = 0; j < 4; j++) {
            int n = bn + tx * 4 + j;
            float v = acc[i][j] + bias[n];
            if (GELU) {
                float u = v;
                v = 0.5f * u * (1.f + tanhf(0.7978845608f * (u + 0.044715f * u * u * u)));
            }
            if (RES) v += res[(long)m * N + n];
            out[(long)m * N + n] = v;
        }
    }
}

// ---------------- GEMM NT (lm_head): out[M,N] = A[M,K] @ Wt[N,K]^T, no bias ------
__global__ __launch_bounds__(256) void gemm_nt(const float* __restrict__ A,
                                               const float* __restrict__ Wt,
                                               float* __restrict__ out,
                                               int N, int K) {
    __shared__ float As[16][64];
    __shared__ float Bs[16][64];
    int tid = threadIdx.x;
    int tx = tid & 15, ty = tid >> 4;
    int bm = blockIdx.y * 64, bn = blockIdx.x * 64;
    float acc[4][4] = {};
    int arow = tid >> 2, acol = (tid & 3) * 4;

    for (int k0 = 0; k0 < K; k0 += 16) {
        float4 av = *(const float4*)&A[(long)(bm + arow) * K + k0 + acol];
        int wn = bn + arow;
        float4 wv = make_float4(0.f, 0.f, 0.f, 0.f);
        if (wn < N) wv = *(const float4*)&Wt[(long)wn * K + k0 + acol];
        As[acol + 0][arow] = av.x;
        As[acol + 1][arow] = av.y;
        As[acol + 2][arow] = av.z;
        As[acol + 3][arow] = av.w;
        Bs[acol + 0][arow] = wv.x;
        Bs[acol + 1][arow] = wv.y;
        Bs[acol + 2][arow] = wv.z;
        Bs[acol + 3][arow] = wv.w;
        __syncthreads();
#pragma unroll
        for (int kk = 0; kk < 16; kk++) {
            float4 a4 = *(const float4*)&As[kk][ty * 4];
            float4 w4 = *(const float4*)&Bs[kk][tx * 4];
            float am[4] = {a4.x, a4.y, a4.z, a4.w};
            float wn4[4] = {w4.x, w4.y, w4.z, w4.w};
#pragma unroll
            for (int i = 0; i < 4; i++)
#pragma unroll
                for (int j = 0; j < 4; j++) acc[i][j] = fmaf(am[i], wn4[j], acc[i][j]);
        }
        __syncthreads();
    }
#pragma unroll
    for (int i = 0; i < 4; i++) {
        int m = bm + ty * 4 + i;
#pragma unroll
        for (int j = 0; j < 4; j++) {
            int n = bn + tx * 4 + j;
            if (n < N) out[(long)m * N + n] = acc[i][j];
        }
    }
}

// ---------------- fused causal attention (flash-style, 1 wave per query row) -----
// qkv layout (B,T,3C): q at +0, k at +C, v at +2C; head h occupies cols h*64..h*64+63
__global__ __launch_bounds__(256) void attn_k(const float* __restrict__ qkv,
                                              float* __restrict__ y) {
    int wid = threadIdx.x >> 6, lane = threadIdx.x & 63;
    int bh = blockIdx.x / (TT / 4);  // 0..B*H-1 ; 4 consecutive q rows share K/V in L1
    int qg = blockIdx.x % (TT / 4);
    int q = qg * 4 + wid;
    int h = bh % HH, b = bh / HH;

    __shared__ float qs[4][HD];
    qs[wid][lane] = qkv[((long)(b * TT + q)) * (3 * CC) + h * HD + lane];
    __syncthreads();

    float o = 0.f, m = -INFINITY, ssum = 0.f;
    const float scale = 0.125f;  // HD^-0.5

    for (int k0 = 0; k0 <= q; k0 += 64) {
        int k = k0 + lane;
        float sc = -INFINITY;
        if (k <= q) {
            const float* kp = qkv + ((long)(b * TT + k)) * (3 * CC) + CC + h * HD;
            float d = 0.f;
#pragma unroll
            for (int dd = 0; dd < HD; dd++) d = fmaf(qs[wid][dd], kp[dd], d);
            sc = d * scale;
        }
        float tmax = wave_max(sc);
        float nm = fmaxf(m, tmax);
        float p = (k <= q) ? expf(sc - nm) : 0.f;
        float tsum = wave_sum(p);
        float resc = expf(m - nm);  // first iter: exp(-inf)=0, o already 0
        ssum = ssum * resc + tsum;
        o *= resc;
        int kmax = min(63, q - k0);
        const float* vp = qkv + ((long)(b * TT + k0)) * (3 * CC) + 2 * CC + h * HD + lane;
        for (int kk = 0; kk <= kmax; kk++) {
            float pk = __shfl(p, kk, 64);
            o = fmaf(pk, vp[(long)kk * 3 * CC], o);
        }
        m = nm;
    }
    y[((long)(b * TT + q)) * CC + h * HD + lane] = o / ssum;
}

// ---------------- host side ----------------
extern "C" void kernel_launch(void* const* d_in, const int* in_sizes, int n_in,
                              void* d_out, int out_size, void* d_ws, size_t ws_size,
                              hipStream_t stream) {
    const int* idx = (const int*)d_in[0];
    const float* wte = (const float*)d_in[1];
    const float* wpe = (const float*)d_in[2];
    const float* ln1_w = (const float*)d_in[3];
    const float* ln1_b = (const float*)d_in[4];
    const float* attn_w = (const float*)d_in[5];
    const float* attn_b = (const float*)d_in[6];
    const float* proj_w = (const float*)d_in[7];
    const float* proj_b = (const float*)d_in[8];
    const float* ln2_w = (const float*)d_in[9];
    const float* ln2_b = (const float*)d_in[10];
    const float* fc_w = (const float*)d_in[11];
    const float* fc_b = (const float*)d_in[12];
    const float* fcp_w = (const float*)d_in[13];
    const float* fcp_b = (const float*)d_in[14];
    const float* lnf_w = (const float*)d_in[15];
    const float* lnf_b = (const float*)d_in[16];
    float* out = (float*)d_out;

    // scratch: x,h always in ws; qkv/ff in ws if it fits, else carved from the
    // tail of d_out (dead before lm_head writes out).
    float* x = (float*)d_ws;
    float* h = x + (long)BT * CC;
    size_t need = ((size_t)BT * CC * 2 + (size_t)BT * 3 * CC + (size_t)BT * 4 * CC) * sizeof(float);
    float *qkvb, *ffb;
    if (ws_size >= need) {
        qkvb = h + (long)BT * CC;
        ffb = qkvb + (long)BT * 3 * CC;
    } else {
        float* tail = out + (size_t)out_size;
        ffb = tail - (size_t)BT * 4 * CC;
        qkvb = ffb - (size_t)BT * 3 * CC;
    }

    embed_k<<<BT, 256, 0, stream>>>(idx, wte, wpe, x);

    for (int l = 0; l < LL; l++) {
        ln_k<<<BT, 256, 0, stream>>>(x, ln1_w + l * CC, ln1_b + l * CC, h);
        gemm_nn<false, false><<<dim3(3 * CC / 64, BT / 64), 256, 0, stream>>>(
            h, attn_w + (long)l * CC * 3 * CC, attn_b + (long)l * 3 * CC, nullptr,
            qkvb, 3 * CC, CC);
        attn_k<<<BB * HH * (TT / 4), 256, 0, stream>>>(qkvb, h);  // y -> h
        gemm_nn<false, true><<<dim3(CC / 64, BT / 64), 256, 0, stream>>>(
            h, proj_w + (long)l * CC * CC, proj_b + (long)l * CC, x, x, CC, CC);
        ln_k<<<BT, 256, 0, stream>>>(x, ln2_w + l * CC, ln2_b + l * CC, h);
        gemm_nn<true, false><<<dim3(4 * CC / 64, BT / 64), 256, 0, stream>>>(
            h, fc_w + (long)l * CC * 4 * CC, fc_b + (long)l * 4 * CC, nullptr,
            ffb, 4 * CC, CC);
        gemm_nn<false, true><<<dim3(CC / 64, BT / 64), 256, 0, stream>>>(
            ffb, fcp_w + (long)l * 4 * CC * CC, fcp_b + (long)l * CC, x, x, CC, 4 * CC);
    }

    ln_k<<<BT, 256, 0, stream>>>(x, lnf_w, lnf_b, h);
    gemm_nt<<<dim3((VV + 63) / 64, BT / 64), 256, 0, stream>>>(h, wte, out, VV, CC);
}

// Round 2
// 7436.574 us; speedup vs baseline: 2.2857x; 2.2857x over previous
//
#include <hip/hip_runtime.h>
#include <math.h>

// GPT-2 small forward. Split-bf16 MFMA GEMMs + LDS-staged attention.
#define VV 50257
#define CC 768
#define LL 12
#define HH 12
#define TT 1024
#define BB 2
#define BT 2048
#define HD 64

typedef unsigned short u16;
using bf8 = __attribute__((ext_vector_type(8))) short;   // 8 bf16 (4 VGPRs)
using f32x4 = __attribute__((ext_vector_type(4))) float; // MFMA acc

__device__ __forceinline__ u16 bf16_rne(float f) {
    unsigned u = __float_as_uint(f);
    unsigned r = u + 0x7FFF + ((u >> 16) & 1);
    return (u16)(r >> 16);
}
__device__ __forceinline__ float bf16_tof(u16 s) {
    return __uint_as_float(((unsigned)s) << 16);
}
__device__ __forceinline__ void split2(float f, u16& h, u16& l) {
    h = bf16_rne(f);
    l = bf16_rne(f - bf16_tof(h));
}
__device__ __forceinline__ float gelu_f(float u) {
    return 0.5f * u * (1.f + tanhf(0.7978845608f * (u + 0.044715f * u * u * u)));
}
__device__ __forceinline__ float wave_sum(float v) {
#pragma unroll
    for (int off = 1; off < 64; off <<= 1) v += __shfl_xor(v, off, 64);
    return v;
}
__device__ __forceinline__ float wave_max(float v) {
#pragma unroll
    for (int off = 1; off < 64; off <<= 1) v = fmaxf(v, __shfl_xor(v, off, 64));
    return v;
}

// ---------------- embedding ----------------
__global__ __launch_bounds__(256) void embed_k(const int* __restrict__ idx,
                                               const float* __restrict__ wte,
                                               const float* __restrict__ wpe,
                                               float* __restrict__ x) {
    int row = blockIdx.x;
    int t = row & (TT - 1);
    long tok = idx[row];
    const float* a = wte + tok * (long)CC;
    const float* p = wpe + (long)t * CC;
    float* d = x + (long)row * CC;
    for (int c = threadIdx.x; c < CC; c += 256) d[c] = a[c] + p[c];
}

// ---------------- layernorm -> split bf16 planes ----------------
__global__ __launch_bounds__(256) void ln_k(const float* __restrict__ in,
                                            const float* __restrict__ w,
                                            const float* __restrict__ b,
                                            u16* __restrict__ oh, u16* __restrict__ ol) {
    int row = blockIdx.x;
    const float* src = in + (long)row * CC;
    float v[3];
    float s = 0.f, sq = 0.f;
#pragma unroll
    for (int i = 0; i < 3; i++) {
        v[i] = src[threadIdx.x + 256 * i];
        s += v[i];
        sq += v[i] * v[i];
    }
    s = wave_sum(s);
    sq = wave_sum(sq);
    __shared__ float ls[4], lq[4];
    int wid = threadIdx.x >> 6, lane = threadIdx.x & 63;
    if (lane == 0) { ls[wid] = s; lq[wid] = sq; }
    __syncthreads();
    s = ls[0] + ls[1] + ls[2] + ls[3];
    sq = lq[0] + lq[1] + lq[2] + lq[3];
    float mean = s * (1.f / CC);
    float var = sq * (1.f / CC) - mean * mean;
    float rstd = rsqrtf(var + 1e-5f);
#pragma unroll
    for (int i = 0; i < 3; i++) {
        int c = threadIdx.x + 256 * i;
        float val = (v[i] - mean) * rstd * w[c] + b[c];
        u16 hh, lo;
        split2(val, hh, lo);
        oh[(long)row * CC + c] = hh;
        ol[(long)row * CC + c] = lo;
    }
}

// ------- weight transpose + hi/lo split: W[K,N] fp32 -> Wt_hi/lo [N,K] bf16 -------
__global__ __launch_bounds__(256) void tsplit(const float* __restrict__ W,
                                              u16* __restrict__ Dh,
                                              int K, int N, long wstride, long ostride) {
    __shared__ float tile[16][65];
    int t = threadIdx.x;
    int k0 = blockIdx.y * 16, n0 = blockIdx.x * 64;
    const float* src = W + (long)blockIdx.z * wstride;
    u16* dh = Dh + (long)blockIdx.z * ostride;
    u16* dl = dh + (long)K * N;
    {
        int k = t >> 4, n4 = (t & 15) * 4;
        float4 v = *(const float4*)&src[(long)(k0 + k) * N + n0 + n4];
        tile[k][n4] = v.x; tile[k][n4 + 1] = v.y; tile[k][n4 + 2] = v.z; tile[k][n4 + 3] = v.w;
    }
    __syncthreads();
    int n = t >> 2, kq = (t & 3) * 4;
    u16 h[4], l[4];
#pragma unroll
    for (int j = 0; j < 4; j++) split2(tile[kq + j][n], h[j], l[j]);
    long off = (long)(n0 + n) * K + k0 + kq;
    *(uint2*)&dh[off] = make_uint2((unsigned)h[0] | ((unsigned)h[1] << 16),
                                   (unsigned)h[2] | ((unsigned)h[3] << 16));
    *(uint2*)&dl[off] = make_uint2((unsigned)l[0] | ((unsigned)l[1] << 16),
                                   (unsigned)l[2] | ((unsigned)l[3] << 16));
}

// ---------------- split-bf16 MFMA GEMM: C[M,N] = A[M,K] * B[N,K]^T ----------------
// A,B given as hi/lo bf16 planes, [*,K] row-major. 128x128 tile, BK=32, 4 waves.
// EPI: 0 bias->f32, 1 bias+res->f32, 2 bias+gelu->split planes
template <int EPI>
__global__ __launch_bounds__(256, 2) void gemm_mfma(
    const u16* __restrict__ Ah, const u16* __restrict__ Al,
    const u16* __restrict__ Bh, const u16* __restrict__ Bl,
    const float* __restrict__ bias, const float* __restrict__ res,
    float* __restrict__ outf, u16* __restrict__ oh, u16* __restrict__ ol,
    int N, int K) {
    __shared__ u16 lds[16][1040];  // [mat*4+kg][row*8+j], mat:0=Ah 1=Al 2=Bh 3=Bl
    int tid = threadIdx.x, lane = tid & 63, wid = tid >> 6;
    long bm = (long)blockIdx.y * 128, bn = (long)blockIdx.x * 128;
    const u16* srcs[4] = {Ah + bm * K, Al + bm * K, Bh + bn * K, Bl + bn * K};
    f32x4 acc[4][4];
#pragma unroll
    for (int i = 0; i < 4; i++)
#pragma unroll
        for (int j = 0; j < 4; j++) acc[i][j] = (f32x4){0.f, 0.f, 0.f, 0.f};
    int wr = (wid >> 1) * 64, wc = (wid & 1) * 64;
    int lrow = lane & 15, lkg = lane >> 4;

    for (int k0 = 0; k0 < K; k0 += 32) {
#pragma unroll
        for (int mat = 0; mat < 4; mat++)
#pragma unroll
            for (int i = 0; i < 2; i++) {
                int slot = tid + 256 * i;
                int row = slot >> 2, kg = slot & 3;
                int4 v = *(const int4*)(srcs[mat] + (long)row * K + k0 + kg * 8);
                *(int4*)&lds[mat * 4 + kg][row * 8] = v;
            }
        __syncthreads();
        bf8 ah[4], al[4], bh[4], bl[4];
#pragma unroll
        for (int m = 0; m < 4; m++) {
            ah[m] = *(const bf8*)&lds[0 + lkg][(wr + m * 16 + lrow) * 8];
            al[m] = *(const bf8*)&lds[4 + lkg][(wr + m * 16 + lrow) * 8];
            bh[m] = *(const bf8*)&lds[8 + lkg][(wc + m * 16 + lrow) * 8];
            bl[m] = *(const bf8*)&lds[12 + lkg][(wc + m * 16 + lrow) * 8];
        }
#pragma unroll
        for (int m = 0; m < 4; m++)
#pragma unroll
            for (int n = 0; n < 4; n++) {
                acc[m][n] = __builtin_amdgcn_mfma_f32_16x16x32_bf16(al[m], bh[n], acc[m][n], 0, 0, 0);
                acc[m][n] = __builtin_amdgcn_mfma_f32_16x16x32_bf16(ah[m], bl[n], acc[m][n], 0, 0, 0);
                acc[m][n] = __builtin_amdgcn_mfma_f32_16x16x32_bf16(ah[m], bh[n], acc[m][n], 0, 0, 0);
            }
        __syncthreads();
    }
#pragma unroll
    for (int m = 0; m < 4; m++)
#pragma unroll
        for (int n = 0; n < 4; n++)
#pragma unroll
            for (int r = 0; r < 4; r++) {
                long row = bm + wr + m * 16 + (lane >> 4) * 4 + r;
                long col = bn + wc + n * 16 + (lane & 15);
                float v = acc[m][n][r] + bias[col];
                long off = row * N + col;
                if (EPI == 0) outf[off] = v;
                if (EPI == 1) outf[off] = v + res[off];
                if (EPI == 2) {
                    float g = gelu_f(v);
                    u16 hh, lo;
                    split2(g, hh, lo);
                    oh[off] = hh;
                    ol[off] = lo;
                }
            }
}

// ---------------- lm_head: A(split planes) @ wte(fp32,[V,C])^T -> fp32 ----------------
__global__ __launch_bounds__(256, 2) void gemm_lmh(const u16* __restrict__ Ah,
                                                   const u16* __restrict__ Al,
                                                   const float* __restrict__ W,
                                                   float* __restrict__ outf) {
    __shared__ u16 lds[16][1040];
    int tid = threadIdx.x, lane = tid & 63, wid = tid >> 6;
    long bm = (long)blockIdx.y * 128, bn = (long)blockIdx.x * 128;
    const int K = CC;
    const u16* srcs[2] = {Ah + bm * K, Al + bm * K};
    f32x4 acc[4][4];
#pragma unroll
    for (int i = 0; i < 4; i++)
#pragma unroll
        for (int j = 0; j < 4; j++) acc[i][j] = (f32x4){0.f, 0.f, 0.f, 0.f};
    int wr = (wid >> 1) * 64, wc = (wid & 1) * 64;
    int lrow = lane & 15, lkg = lane >> 4;

    for (int k0 = 0; k0 < K; k0 += 32) {
#pragma unroll
        for (int mat = 0; mat < 2; mat++)
#pragma unroll
            for (int i = 0; i < 2; i++) {
                int slot = tid + 256 * i;
                int row = slot >> 2, kg = slot & 3;
                int4 v = *(const int4*)(srcs[mat] + (long)row * K + k0 + kg * 8);
                *(int4*)&lds[mat * 4 + kg][row * 8] = v;
            }
#pragma unroll
        for (int i = 0; i < 4; i++) {
            int f = tid + 256 * i;  // 0..1023 float4 slots of 128x32 fp32 B tile
            int row = f >> 3, c4 = f & 7;
            long srow = bn + row;
            if (srow >= VV) srow = VV - 1;
            float4 v = *(const float4*)&W[srow * (long)CC + k0 + c4 * 4];
            u16 h0, l0, h1, l1, h2, l2, h3, l3;
            split2(v.x, h0, l0); split2(v.y, h1, l1);
            split2(v.z, h2, l2); split2(v.w, h3, l3);
            int kg = c4 >> 1, jo = (c4 & 1) * 4;
            *(uint2*)&lds[8 + kg][row * 8 + jo] =
                make_uint2((unsigned)h0 | ((unsigned)h1 << 16), (unsigned)h2 | ((unsigned)h3 << 16));
            *(uint2*)&lds[12 + kg][row * 8 + jo] =
                make_uint2((unsigned)l0 | ((unsigned)l1 << 16), (unsigned)l2 | ((unsigned)l3 << 16));
        }
        __syncthreads();
        bf8 ah[4], al[4], bh[4], bl[4];
#pragma unroll
        for (int m = 0; m < 4; m++) {
            ah[m] = *(const bf8*)&lds[0 + lkg][(wr + m * 16 + lrow) * 8];
            al[m] = *(const bf8*)&lds[4 + lkg][(wr + m * 16 + lrow) * 8];
            bh[m] = *(const bf8*)&lds[8 + lkg][(wc + m * 16 + lrow) * 8];
            bl[m] = *(const bf8*)&lds[12 + lkg][(wc + m * 16 + lrow) * 8];
        }
#pragma unroll
        for (int m = 0; m < 4; m++)
#pragma unroll
            for (int n = 0; n < 4; n++) {
                acc[m][n] = __builtin_amdgcn_mfma_f32_16x16x32_bf16(al[m], bh[n], acc[m][n], 0, 0, 0);
                acc[m][n] = __builtin_amdgcn_mfma_f32_16x16x32_bf16(ah[m], bl[n], acc[m][n], 0, 0, 0);
                acc[m][n] = __builtin_amdgcn_mfma_f32_16x16x32_bf16(ah[m], bh[n], acc[m][n], 0, 0, 0);
            }
        __syncthreads();
    }
#pragma unroll
    for (int m = 0; m < 4; m++)
#pragma unroll
        for (int n = 0; n < 4; n++)
#pragma unroll
            for (int r = 0; r < 4; r++) {
                long row = bm + wr + m * 16 + (lane >> 4) * 4 + r;
                long col = bn + wc + n * 16 + (lane & 15);
                if (col < VV) outf[row * (long)VV + col] = acc[m][n][r];
            }
}

// ---------------- attention: LDS-staged K/V, 16 q-rows per block ----------------
__global__ __launch_bounds__(256) void attn2(const float* __restrict__ qkv,
                                             u16* __restrict__ yh, u16* __restrict__ yl) {
    __shared__ float qs[16][65], Kt[64][65], Vt[64][65], ps[4][4][64];
    int tid = threadIdx.x, lane = tid & 63, wid = tid >> 6;
    int bh = blockIdx.x >> 6, qg = blockIdx.x & 63;
    int b = bh / HH, hh = bh % HH;
    int qbase = qg * 16;
    const float* base = qkv + (long)b * TT * 3 * CC + hh * HD;
    {
        int r = tid >> 4, d4 = (tid & 15) * 4;
        float4 v = *(const float4*)&base[(long)(qbase + r) * (3 * CC) + d4];
        qs[r][d4] = v.x; qs[r][d4 + 1] = v.y; qs[r][d4 + 2] = v.z; qs[r][d4 + 3] = v.w;
    }
    float o[4] = {0.f, 0.f, 0.f, 0.f};
    float mm[4] = {-INFINITY, -INFINITY, -INFINITY, -INFINITY};
    float sden[4] = {0.f, 0.f, 0.f, 0.f};
    int r0 = qbase + wid * 4;
    for (int k0 = 0; k0 <= qbase + 15; k0 += 64) {
        __syncthreads();
#pragma unroll
        for (int i = 0; i < 8; i++) {
            int f = tid + 256 * i;
            int kk = (f >> 4) & 63, d4 = (f & 15) * 4, isv = f >> 10;
            float4 v = *(const float4*)&base[(long)(k0 + kk) * (3 * CC) + CC + isv * CC + d4];
            float* dst = isv ? &Vt[kk][d4] : &Kt[kk][d4];
            dst[0] = v.x; dst[1] = v.y; dst[2] = v.z; dst[3] = v.w;
        }
        __syncthreads();
        float s[4] = {0.f, 0.f, 0.f, 0.f};
#pragma unroll 16
        for (int d = 0; d < 64; d++) {
            float kd = Kt[lane][d];
#pragma unroll
            for (int i = 0; i < 4; i++) s[i] = fmaf(qs[wid * 4 + i][d], kd, s[i]);
        }
#pragma unroll
        for (int i = 0; i < 4; i++) {
            int qrow = r0 + i;
            bool ok = (k0 + lane) <= qrow;
            float sc = ok ? s[i] * 0.125f : -INFINITY;
            float nm = fmaxf(mm[i], wave_max(sc));
            float p = ok ? expf(sc - nm) : 0.f;
            float ts = wave_sum(p);
            float rs = expf(mm[i] - nm);
            sden[i] = sden[i] * rs + ts;
            o[i] *= rs;
            mm[i] = nm;
            ps[wid][i][lane] = p;
        }
#pragma unroll 16
        for (int kk = 0; kk < 64; kk++) {
            float vv = Vt[kk][lane];
#pragma unroll
            for (int i = 0; i < 4; i++) o[i] = fmaf(ps[wid][i][kk], vv, o[i]);
        }
    }
#pragma unroll
    for (int i = 0; i < 4; i++) {
        float val = o[i] / sden[i];
        long off = (long)(b * TT + r0 + i) * CC + hh * HD + lane;
        u16 hi, lo;
        split2(val, hi, lo);
        yh[off] = hi;
        yl[off] = lo;
    }
}

// ---------------- host ----------------
extern "C" void kernel_launch(void* const* d_in, const int* in_sizes, int n_in,
                              void* d_out, int out_size, void* d_ws, size_t ws_size,
                              hipStream_t stream) {
    const int* idx = (const int*)d_in[0];
    const float* wte = (const float*)d_in[1];
    const float* wpe = (const float*)d_in[2];
    const float* ln1_w = (const float*)d_in[3];
    const float* ln1_b = (const float*)d_in[4];
    const float* attn_w = (const float*)d_in[5];
    const float* attn_b = (const float*)d_in[6];
    const float* proj_w = (const float*)d_in[7];
    const float* proj_b = (const float*)d_in[8];
    const float* ln2_w = (const float*)d_in[9];
    const float* ln2_b = (const float*)d_in[10];
    const float* fc_w = (const float*)d_in[11];
    const float* fc_b = (const float*)d_in[12];
    const float* fcp_w = (const float*)d_in[13];
    const float* fcp_b = (const float*)d_in[14];
    const float* lnf_w = (const float*)d_in[15];
    const float* lnf_b = (const float*)d_in[16];
    float* out = (float*)d_out;

    // split weights live in the tail of d_out (dead before lm_head writes out)
    const long WB_LAYER = 14155776;  // ushorts per layer (hi+lo of 4 matrices)
    const size_t wb_bytes = (size_t)LL * WB_LAYER * 2;  // 339.7 MB
    char* out_end = (char*)d_out + (size_t)out_size * 4;
    u16* wb = (u16*)(out_end - wb_bytes);

    // activations: h planes always in ws (needed during lm_head); rest in ws if it
    // fits, else carved from d_out just below wb (all dead before lm_head).
    size_t h_plane = (size_t)BT * CC * 2;
    size_t x_b = (size_t)BT * CC * 4;
    size_t ff_plane = (size_t)BT * 4 * CC * 2;
    size_t qkv_b = (size_t)BT * 3 * CC * 4;
    size_t act_rest = x_b + 2 * ff_plane + qkv_b;  // 50.3 MB
    u16* h_hi = (u16*)d_ws;
    u16* h_lo = h_hi + (size_t)BT * CC;
    char* rest = (ws_size >= 2 * h_plane + act_rest) ? ((char*)d_ws + 2 * h_plane)
                                                     : ((char*)wb - act_rest);
    float* x = (float*)rest;
    u16* ff_hi = (u16*)(rest + x_b);
    u16* ff_lo = ff_hi + (size_t)BT * 4 * CC;
    float* qkvb = (float*)(rest + x_b + 2 * ff_plane);

    // one-time weight transpose+split (all layers, 4 matrix types)
    tsplit<<<dim3(36, 48, 12), 256, 0, stream>>>(attn_w, wb + 0, CC, 3 * CC, (long)CC * 3 * CC, WB_LAYER);
    tsplit<<<dim3(12, 48, 12), 256, 0, stream>>>(proj_w, wb + 3538944, CC, CC, (long)CC * CC, WB_LAYER);
    tsplit<<<dim3(48, 48, 12), 256, 0, stream>>>(fc_w, wb + 4718592, CC, 4 * CC, (long)CC * 4 * CC, WB_LAYER);
    tsplit<<<dim3(12, 192, 12), 256, 0, stream>>>(fcp_w, wb + 9437184, 4 * CC, CC, (long)4 * CC * CC, WB_LAYER);

    embed_k<<<BT, 256, 0, stream>>>(idx, wte, wpe, x);

    for (int l = 0; l < LL; l++) {
        u16* wl = wb + (long)l * WB_LAYER;
        u16 *aw_h = wl, *aw_l = wl + 1769472;
        u16 *pw_h = wl + 3538944, *pw_l = pw_h + 589824;
        u16 *fw_h = wl + 4718592, *fw_l = fw_h + 2359296;
        u16 *qw_h = wl + 9437184, *qw_l = qw_h + 2359296;

        ln_k<<<BT, 256, 0, stream>>>(x, ln1_w + l * CC, ln1_b + l * CC, h_hi, h_lo);
        gemm_mfma<0><<<dim3(18, 16), 256, 0, stream>>>(h_hi, h_lo, aw_h, aw_l,
            attn_b + (long)l * 3 * CC, nullptr, qkvb, nullptr, nullptr, 3 * CC, CC);
        attn2<<<BB * HH * 64, 256, 0, stream>>>(qkvb, h_hi, h_lo);
        gemm_mfma<1><<<dim3(6, 16), 256, 0, stream>>>(h_hi, h_lo, pw_h, pw_l,
            proj_b + (long)l * CC, x, x, nullptr, nullptr, CC, CC);
        ln_k<<<BT, 256, 0, stream>>>(x, ln2_w + l * CC, ln2_b + l * CC, h_hi, h_lo);
        gemm_mfma<2><<<dim3(24, 16), 256, 0, stream>>>(h_hi, h_lo, fw_h, fw_l,
            fc_b + (long)l * 4 * CC, nullptr, nullptr, ff_hi, ff_lo, 4 * CC, CC);
        gemm_mfma<1><<<dim3(6, 16), 256, 0, stream>>>(ff_hi, ff_lo, qw_h, qw_l,
            fcp_b + (long)l * CC, x, x, nullptr, nullptr, CC, 4 * CC);
    }

    ln_k<<<BT, 256, 0, stream>>>(x, lnf_w, lnf_b, h_hi, h_lo);
    gemm_lmh<<<dim3(393, 16), 256, 0, stream>>>(h_hi, h_lo, wte, out);
}

// Round 3
// 7186.806 us; speedup vs baseline: 2.3651x; 1.0348x over previous
//
#include <hip/hip_runtime.h>
#include <math.h>

// GPT-2 small forward. Split-bf16 MFMA GEMMs (global_load_lds staging,
// XOR-swizzled LDS) + LDS-staged attention.
#define VV 50257
#define CC 768
#define LL 12
#define HH 12
#define TT 1024
#define BB 2
#define BT 2048
#define HD 64

typedef unsigned short u16;
using bf8 = __attribute__((ext_vector_type(8))) short;   // 8 bf16 (4 VGPRs)
using f32x4 = __attribute__((ext_vector_type(4))) float; // MFMA acc

__device__ __forceinline__ u16 bf16_rne(float f) {
    unsigned u = __float_as_uint(f);
    unsigned r = u + 0x7FFF + ((u >> 16) & 1);
    return (u16)(r >> 16);
}
__device__ __forceinline__ float bf16_tof(u16 s) {
    return __uint_as_float(((unsigned)s) << 16);
}
__device__ __forceinline__ void split2(float f, u16& h, u16& l) {
    h = bf16_rne(f);
    l = bf16_rne(f - bf16_tof(h));
}
__device__ __forceinline__ float gelu_f(float u) {
    return 0.5f * u * (1.f + tanhf(0.7978845608f * (u + 0.044715f * u * u * u)));
}
__device__ __forceinline__ float wave_sum(float v) {
#pragma unroll
    for (int off = 1; off < 64; off <<= 1) v += __shfl_xor(v, off, 64);
    return v;
}
__device__ __forceinline__ float wave_max(float v) {
#pragma unroll
    for (int off = 1; off < 64; off <<= 1) v = fmaxf(v, __shfl_xor(v, off, 64));
    return v;
}

// async global->LDS, 16B per lane. ldst must be wave-uniform; gsrc is per-lane.
__device__ __forceinline__ void gload16(const void* gsrc, void* ldst) {
    __builtin_amdgcn_global_load_lds(
        (const __attribute__((address_space(1))) void*)gsrc,
        (__attribute__((address_space(3))) void*)ldst, 16, 0, 0);
}

// ---------------- embedding ----------------
__global__ __launch_bounds__(256) void embed_k(const int* __restrict__ idx,
                                               const float* __restrict__ wte,
                                               const float* __restrict__ wpe,
                                               float* __restrict__ x) {
    int row = blockIdx.x;
    int t = row & (TT - 1);
    long tok = idx[row];
    const float* a = wte + tok * (long)CC;
    const float* p = wpe + (long)t * CC;
    float* d = x + (long)row * CC;
    for (int c = threadIdx.x; c < CC; c += 256) d[c] = a[c] + p[c];
}

// ---------------- layernorm -> split bf16 planes ----------------
__global__ __launch_bounds__(256) void ln_k(const float* __restrict__ in,
                                            const float* __restrict__ w,
                                            const float* __restrict__ b,
                                            u16* __restrict__ oh, u16* __restrict__ ol) {
    int row = blockIdx.x;
    const float* src = in + (long)row * CC;
    float v[3];
    float s = 0.f, sq = 0.f;
#pragma unroll
    for (int i = 0; i < 3; i++) {
        v[i] = src[threadIdx.x + 256 * i];
        s += v[i];
        sq += v[i] * v[i];
    }
    s = wave_sum(s);
    sq = wave_sum(sq);
    __shared__ float ls[4], lq[4];
    int wid = threadIdx.x >> 6, lane = threadIdx.x & 63;
    if (lane == 0) { ls[wid] = s; lq[wid] = sq; }
    __syncthreads();
    s = ls[0] + ls[1] + ls[2] + ls[3];
    sq = lq[0] + lq[1] + lq[2] + lq[3];
    float mean = s * (1.f / CC);
    float var = sq * (1.f / CC) - mean * mean;
    float rstd = rsqrtf(var + 1e-5f);
#pragma unroll
    for (int i = 0; i < 3; i++) {
        int c = threadIdx.x + 256 * i;
        float val = (v[i] - mean) * rstd * w[c] + b[c];
        u16 hh, lo;
        split2(val, hh, lo);
        oh[(long)row * CC + c] = hh;
        ol[(long)row * CC + c] = lo;
    }
}

// ------- weight transpose + hi/lo split: W[K,N] fp32 -> Wt_hi/lo [N,K] bf16 -------
__global__ __launch_bounds__(256) void tsplit(const float* __restrict__ W,
                                              u16* __restrict__ Dh,
                                              int K, int N, long wstride, long ostride) {
    __shared__ float tile[16][65];
    int t = threadIdx.x;
    int k0 = blockIdx.y * 16, n0 = blockIdx.x * 64;
    const float* src = W + (long)blockIdx.z * wstride;
    u16* dh = Dh + (long)blockIdx.z * ostride;
    u16* dl = dh + (long)K * N;
    {
        int k = t >> 4, n4 = (t & 15) * 4;
        float4 v = *(const float4*)&src[(long)(k0 + k) * N + n0 + n4];
        tile[k][n4] = v.x; tile[k][n4 + 1] = v.y; tile[k][n4 + 2] = v.z; tile[k][n4 + 3] = v.w;
    }
    __syncthreads();
    int n = t >> 2, kq = (t & 3) * 4;
    u16 h[4], l[4];
#pragma unroll
    for (int j = 0; j < 4; j++) split2(tile[kq + j][n], h[j], l[j]);
    long off = (long)(n0 + n) * K + k0 + kq;
    *(uint2*)&dh[off] = make_uint2((unsigned)h[0] | ((unsigned)h[1] << 16),
                                   (unsigned)h[2] | ((unsigned)h[3] << 16));
    *(uint2*)&dl[off] = make_uint2((unsigned)l[0] | ((unsigned)l[1] << 16),
                                   (unsigned)l[2] | ((unsigned)l[3] << 16));
}

// ---------------- split-bf16 MFMA GEMM: C[M,N] = A[M,K] * B[N,K]^T ----------------
// A,B hi/lo bf16 planes, [*,K] row-major. 128x128 tile, BK=32, 4 waves.
// LDS per plane: row-major [128 rows][32 k], 64B/row, k-seg XOR-swizzled:
// byte(row, kseg) = row*64 + (kseg ^ ((row>>1)&3))*16. Stage via global_load_lds
// (linear dest) with inverse-swizzled global source; reads apply the same XOR.
// EPI: 0 bias->f32, 1 bias+res->f32, 2 bias+gelu->split planes
template <int EPI>
__global__ __launch_bounds__(256, 3) void gemm_mfma(
    const u16* __restrict__ Ah, const u16* __restrict__ Al,
    const u16* __restrict__ Bh, const u16* __restrict__ Bl,
    const float* __restrict__ bias, const float* __restrict__ res,
    float* __restrict__ outf, u16* __restrict__ oh, u16* __restrict__ ol,
    int N, int K) {
    __shared__ __attribute__((aligned(16))) u16 lds[4][4096];  // 4 planes x 8KB
    int tid = threadIdx.x, lane = tid & 63, wid = tid >> 6;
    long bm = (long)blockIdx.x * 128, bn = (long)blockIdx.y * 128;
    const u16* srcs[4] = {Ah + bm * K, Al + bm * K, Bh + bn * K, Bl + bn * K};
    f32x4 acc[4][4];
#pragma unroll
    for (int i = 0; i < 4; i++)
#pragma unroll
        for (int j = 0; j < 4; j++) acc[i][j] = (f32x4){0.f, 0.f, 0.f, 0.f};
    int wr = (wid >> 1) * 64, wc = (wid & 1) * 64;
    int lrow = lane & 15, lkg = lane >> 4;

    // staging geometry: slot = i*256 + wid*64 + lane; lds byte = slot*16;
    // row = slot>>2; kseg = slot&3; source k-seg = kseg ^ ((row>>1)&3)
    int slot0 = wid * 64 + lane;
    int row0 = slot0 >> 2, sk0 = (slot0 & 3) ^ ((row0 >> 1) & 3);
    int slot1 = slot0 + 256;
    int row1 = slot1 >> 2, sk1 = (slot1 & 3) ^ ((row1 >> 1) & 3);
    char* lbase0 = (char*)&lds[0][0] + wid * 1024;
    char* lbase1 = lbase0 + 4096;

    for (int k0 = 0; k0 < K; k0 += 32) {
#pragma unroll
        for (int mat = 0; mat < 4; mat++) {
            gload16(srcs[mat] + (long)row0 * K + k0 + sk0 * 8, lbase0 + mat * 8192);
            gload16(srcs[mat] + (long)row1 * K + k0 + sk1 * 8, lbase1 + mat * 8192);
        }
        __syncthreads();
        bf8 ah[4], al[4];
#pragma unroll
        for (int m = 0; m < 4; m++) {
            int r = wr + m * 16 + lrow;
            int off = r * 32 + ((lkg ^ ((r >> 1) & 3)) * 8);
            ah[m] = *(const bf8*)&lds[0][off];
            al[m] = *(const bf8*)&lds[1][off];
        }
#pragma unroll
        for (int n = 0; n < 4; n++) {
            int r = wc + n * 16 + lrow;
            int off = r * 32 + ((lkg ^ ((r >> 1) & 3)) * 8);
            bf8 bh = *(const bf8*)&lds[2][off];
            bf8 bl = *(const bf8*)&lds[3][off];
#pragma unroll
            for (int m = 0; m < 4; m++) {
                acc[m][n] = __builtin_amdgcn_mfma_f32_16x16x32_bf16(al[m], bh, acc[m][n], 0, 0, 0);
                acc[m][n] = __builtin_amdgcn_mfma_f32_16x16x32_bf16(ah[m], bl, acc[m][n], 0, 0, 0);
                acc[m][n] = __builtin_amdgcn_mfma_f32_16x16x32_bf16(ah[m], bh, acc[m][n], 0, 0, 0);
            }
        }
        __syncthreads();
    }
#pragma unroll
    for (int m = 0; m < 4; m++)
#pragma unroll
        for (int n = 0; n < 4; n++)
#pragma unroll
            for (int r = 0; r < 4; r++) {
                long row = bm + wr + m * 16 + (lane >> 4) * 4 + r;
                long col = bn + wc + n * 16 + (lane & 15);
                float v = acc[m][n][r] + bias[col];
                long off = row * N + col;
                if (EPI == 0) outf[off] = v;
                if (EPI == 1) outf[off] = v + res[off];
                if (EPI == 2) {
                    float g = gelu_f(v);
                    u16 hh, lo;
                    split2(g, hh, lo);
                    oh[off] = hh;
                    ol[off] = lo;
                }
            }
}

// ---------------- lm_head: A(split planes) @ wte(fp32,[V,C])^T -> fp32 ----------------
// Linear grid of 6288 blocks; bijective XCD-chunk swizzle; m-fastest so the 16
// blocks sharing a wte n-tile run consecutively on one XCD.
__global__ __launch_bounds__(256, 3) void gemm_lmh(const u16* __restrict__ Ah,
                                                   const u16* __restrict__ Al,
                                                   const float* __restrict__ W,
                                                   float* __restrict__ outf) {
    __shared__ __attribute__((aligned(16))) u16 lds[4][4096];  // Ah, Al, Bh, Bl
    int tid = threadIdx.x, lane = tid & 63, wid = tid >> 6;
    const int NWG8 = (16 * 393) >> 3;  // 786
    int bid = blockIdx.x;
    int wg = (bid & 7) * NWG8 + (bid >> 3);
    long bm = (long)(wg & 15) * 128;
    long bn = (long)(wg >> 4) * 128;
    const int K = CC;
    const u16* srcs[2] = {Ah + bm * K, Al + bm * K};
    f32x4 acc[4][4];
#pragma unroll
    for (int i = 0; i < 4; i++)
#pragma unroll
        for (int j = 0; j < 4; j++) acc[i][j] = (f32x4){0.f, 0.f, 0.f, 0.f};
    int wr = (wid >> 1) * 64, wc = (wid & 1) * 64;
    int lrow = lane & 15, lkg = lane >> 4;

    int slot0 = wid * 64 + lane;
    int row0 = slot0 >> 2, sk0 = (slot0 & 3) ^ ((row0 >> 1) & 3);
    int slot1 = slot0 + 256;
    int row1 = slot1 >> 2, sk1 = (slot1 & 3) ^ ((row1 >> 1) & 3);
    char* lbase0 = (char*)&lds[0][0] + wid * 1024;
    char* lbase1 = lbase0 + 4096;

    for (int k0 = 0; k0 < K; k0 += 32) {
        // A planes via async direct-to-LDS
#pragma unroll
        for (int mat = 0; mat < 2; mat++) {
            gload16(srcs[mat] + (long)row0 * K + k0 + sk0 * 8, lbase0 + mat * 8192);
            gload16(srcs[mat] + (long)row1 * K + k0 + sk1 * 8, lbase1 + mat * 8192);
        }
        // B tile: fp32 wte -> split bf16, swizzled ds_write
#pragma unroll
        for (int i = 0; i < 4; i++) {
            int f = tid + 256 * i;  // float4 slots of 128x32 fp32 tile
            int row = f >> 3, c4 = f & 7;
            long srow = bn + row;
            if (srow >= VV) srow = VV - 1;
            float4 v = *(const float4*)&W[srow * (long)CC + k0 + c4 * 4];
            u16 h0, l0, h1, l1, h2, l2, h3, l3;
            split2(v.x, h0, l0); split2(v.y, h1, l1);
            split2(v.z, h2, l2); split2(v.w, h3, l3);
            int g = c4 >> 1;
            int boff = row * 64 + ((g ^ ((row >> 1) & 3)) * 16) + (c4 & 1) * 8;
            *(uint2*)((char*)&lds[2][0] + boff) =
                make_uint2((unsigned)h0 | ((unsigned)h1 << 16), (unsigned)h2 | ((unsigned)h3 << 16));
            *(uint2*)((char*)&lds[3][0] + boff) =
                make_uint2((unsigned)l0 | ((unsigned)l1 << 16), (unsigned)l2 | ((unsigned)l3 << 16));
        }
        __syncthreads();
        bf8 ah[4], al[4];
#pragma unroll
        for (int m = 0; m < 4; m++) {
            int r = wr + m * 16 + lrow;
            int off = r * 32 + ((lkg ^ ((r >> 1) & 3)) * 8);
            ah[m] = *(const bf8*)&lds[0][off];
            al[m] = *(const bf8*)&lds[1][off];
        }
#pragma unroll
        for (int n = 0; n < 4; n++) {
            int r = wc + n * 16 + lrow;
            int off = r * 32 + ((lkg ^ ((r >> 1) & 3)) * 8);
            bf8 bh = *(const bf8*)&lds[2][off];
            bf8 bl = *(const bf8*)&lds[3][off];
#pragma unroll
            for (int m = 0; m < 4; m++) {
                acc[m][n] = __builtin_amdgcn_mfma_f32_16x16x32_bf16(al[m], bh, acc[m][n], 0, 0, 0);
                acc[m][n] = __builtin_amdgcn_mfma_f32_16x16x32_bf16(ah[m], bl, acc[m][n], 0, 0, 0);
                acc[m][n] = __builtin_amdgcn_mfma_f32_16x16x32_bf16(ah[m], bh, acc[m][n], 0, 0, 0);
            }
        }
        __syncthreads();
    }
#pragma unroll
    for (int m = 0; m < 4; m++)
#pragma unroll
        for (int n = 0; n < 4; n++)
#pragma unroll
            for (int r = 0; r < 4; r++) {
                long row = bm + wr + m * 16 + (lane >> 4) * 4 + r;
                long col = bn + wc + n * 16 + (lane & 15);
                if (col < VV) outf[row * (long)VV + col] = acc[m][n][r];
            }
}

// ---------------- attention: LDS-staged K/V, 16 q-rows per block ----------------
__global__ __launch_bounds__(256) void attn2(const float* __restrict__ qkv,
                                             u16* __restrict__ yh, u16* __restrict__ yl) {
    __shared__ float qs[16][65], Kt[64][65], Vt[64][65], ps[4][4][64];
    int tid = threadIdx.x, lane = tid & 63, wid = tid >> 6;
    int bh = blockIdx.x >> 6, qg = blockIdx.x & 63;
    int b = bh / HH, hh = bh % HH;
    int qbase = qg * 16;
    const float* base = qkv + (long)b * TT * 3 * CC + hh * HD;
    {
        int r = tid >> 4, d4 = (tid & 15) * 4;
        float4 v = *(const float4*)&base[(long)(qbase + r) * (3 * CC) + d4];
        qs[r][d4] = v.x; qs[r][d4 + 1] = v.y; qs[r][d4 + 2] = v.z; qs[r][d4 + 3] = v.w;
    }
    float o[4] = {0.f, 0.f, 0.f, 0.f};
    float mm[4] = {-INFINITY, -INFINITY, -INFINITY, -INFINITY};
    float sden[4] = {0.f, 0.f, 0.f, 0.f};
    int r0 = qbase + wid * 4;
    for (int k0 = 0; k0 <= qbase + 15; k0 += 64) {
        __syncthreads();
#pragma unroll
        for (int i = 0; i < 8; i++) {
            int f = tid + 256 * i;
            int kk = (f >> 4) & 63, d4 = (f & 15) * 4, isv = f >> 10;
            float4 v = *(const float4*)&base[(long)(k0 + kk) * (3 * CC) + CC + isv * CC + d4];
            float* dst = isv ? &Vt[kk][d4] : &Kt[kk][d4];
            dst[0] = v.x; dst[1] = v.y; dst[2] = v.z; dst[3] = v.w;
        }
        __syncthreads();
        float s[4] = {0.f, 0.f, 0.f, 0.f};
#pragma unroll 16
        for (int d = 0; d < 64; d++) {
            float kd = Kt[lane][d];
#pragma unroll
            for (int i = 0; i < 4; i++) s[i] = fmaf(qs[wid * 4 + i][d], kd, s[i]);
        }
#pragma unroll
        for (int i = 0; i < 4; i++) {
            int qrow = r0 + i;
            bool ok = (k0 + lane) <= qrow;
            float sc = ok ? s[i] * 0.125f : -INFINITY;
            float nm = fmaxf(mm[i], wave_max(sc));
            float p = ok ? expf(sc - nm) : 0.f;
            float ts = wave_sum(p);
            float rs = expf(mm[i] - nm);
            sden[i] = sden[i] * rs + ts;
            o[i] *= rs;
            mm[i] = nm;
            ps[wid][i][lane] = p;
        }
#pragma unroll 16
        for (int kk = 0; kk < 64; kk++) {
            float vv = Vt[kk][lane];
#pragma unroll
            for (int i = 0; i < 4; i++) o[i] = fmaf(ps[wid][i][kk], vv, o[i]);
        }
    }
#pragma unroll
    for (int i = 0; i < 4; i++) {
        float val = o[i] / sden[i];
        long off = (long)(b * TT + r0 + i) * CC + hh * HD + lane;
        u16 hi, lo;
        split2(val, hi, lo);
        yh[off] = hi;
        yl[off] = lo;
    }
}

// ---------------- host ----------------
extern "C" void kernel_launch(void* const* d_in, const int* in_sizes, int n_in,
                              void* d_out, int out_size, void* d_ws, size_t ws_size,
                              hipStream_t stream) {
    const int* idx = (const int*)d_in[0];
    const float* wte = (const float*)d_in[1];
    const float* wpe = (const float*)d_in[2];
    const float* ln1_w = (const float*)d_in[3];
    const float* ln1_b = (const float*)d_in[4];
    const float* attn_w = (const float*)d_in[5];
    const float* attn_b = (const float*)d_in[6];
    const float* proj_w = (const float*)d_in[7];
    const float* proj_b = (const float*)d_in[8];
    const float* ln2_w = (const float*)d_in[9];
    const float* ln2_b = (const float*)d_in[10];
    const float* fc_w = (const float*)d_in[11];
    const float* fc_b = (const float*)d_in[12];
    const float* fcp_w = (const float*)d_in[13];
    const float* fcp_b = (const float*)d_in[14];
    const float* lnf_w = (const float*)d_in[15];
    const float* lnf_b = (const float*)d_in[16];
    float* out = (float*)d_out;

    // split weights live in the tail of d_out (dead before lm_head writes out)
    const long WB_LAYER = 14155776;  // ushorts per layer (hi+lo of 4 matrices)
    const size_t wb_bytes = (size_t)LL * WB_LAYER * 2;  // 339.7 MB
    char* out_end = (char*)d_out + (size_t)out_size * 4;
    u16* wb = (u16*)(out_end - wb_bytes);

    size_t h_plane = (size_t)BT * CC * 2;
    size_t x_b = (size_t)BT * CC * 4;
    size_t ff_plane = (size_t)BT * 4 * CC * 2;
    size_t qkv_b = (size_t)BT * 3 * CC * 4;
    size_t act_rest = x_b + 2 * ff_plane + qkv_b;
    u16* h_hi = (u16*)d_ws;
    u16* h_lo = h_hi + (size_t)BT * CC;
    char* rest = (ws_size >= 2 * h_plane + act_rest) ? ((char*)d_ws + 2 * h_plane)
                                                     : ((char*)wb - act_rest);
    float* x = (float*)rest;
    u16* ff_hi = (u16*)(rest + x_b);
    u16* ff_lo = ff_hi + (size_t)BT * 4 * CC;
    float* qkvb = (float*)(rest + x_b + 2 * ff_plane);

    // one-time weight transpose+split (all layers, 4 matrix types)
    tsplit<<<dim3(36, 48, 12), 256, 0, stream>>>(attn_w, wb + 0, CC, 3 * CC, (long)CC * 3 * CC, WB_LAYER);
    tsplit<<<dim3(12, 48, 12), 256, 0, stream>>>(proj_w, wb + 3538944, CC, CC, (long)CC * CC, WB_LAYER);
    tsplit<<<dim3(48, 48, 12), 256, 0, stream>>>(fc_w, wb + 4718592, CC, 4 * CC, (long)CC * 4 * CC, WB_LAYER);
    tsplit<<<dim3(12, 192, 12), 256, 0, stream>>>(fcp_w, wb + 9437184, 4 * CC, CC, (long)4 * CC * CC, WB_LAYER);

    embed_k<<<BT, 256, 0, stream>>>(idx, wte, wpe, x);

    for (int l = 0; l < LL; l++) {
        u16* wl = wb + (long)l * WB_LAYER;
        u16 *aw_h = wl, *aw_l = wl + 1769472;
        u16 *pw_h = wl + 3538944, *pw_l = pw_h + 589824;
        u16 *fw_h = wl + 4718592, *fw_l = fw_h + 2359296;
        u16 *qw_h = wl + 9437184, *qw_l = qw_h + 2359296;

        ln_k<<<BT, 256, 0, stream>>>(x, ln1_w + l * CC, ln1_b + l * CC, h_hi, h_lo);
        gemm_mfma<0><<<dim3(16, 18), 256, 0, stream>>>(h_hi, h_lo, aw_h, aw_l,
            attn_b + (long)l * 3 * CC, nullptr, qkvb, nullptr, nullptr, 3 * CC, CC);
        attn2<<<BB * HH * 64, 256, 0, stream>>>(qkvb, h_hi, h_lo);
        gemm_mfma<1><<<dim3(16, 6), 256, 0, stream>>>(h_hi, h_lo, pw_h, pw_l,
            proj_b + (long)l * CC, x, x, nullptr, nullptr, CC, CC);
        ln_k<<<BT, 256, 0, stream>>>(x, ln2_w + l * CC, ln2_b + l * CC, h_hi, h_lo);
        gemm_mfma<2><<<dim3(16, 24), 256, 0, stream>>>(h_hi, h_lo, fw_h, fw_l,
            fc_b + (long)l * 4 * CC, nullptr, nullptr, ff_hi, ff_lo, 4 * CC, CC);
        gemm_mfma<1><<<dim3(16, 6), 256, 0, stream>>>(ff_hi, ff_lo, qw_h, qw_l,
            fcp_b + (long)l * CC, x, x, nullptr, nullptr, CC, 4 * CC);
    }

    ln_k<<<BT, 256, 0, stream>>>(x, lnf_w, lnf_b, h_hi, h_lo);
    gemm_lmh<<<dim3(16 * 393), 256, 0, stream>>>(h_hi, h_lo, wte, out);
}